// Round 3
// baseline (1915.368 us; speedup 1.0000x reference)
//
#include <hip/hip_runtime.h>

// Dense dilated KNN graph. B=2, C=64, N=8192, k_total=18, keep ::2 -> 9.
// Strategy: fp32-fma GEMM for candidate top-20/lane, then bit-exact replica
// of numpy's fp32 pipeline to rescore candidates; rank by (dist, idx).
// ws: ptsn [B][N][64] f32 (4 MB) + sqnp [B][N] f32 (64 KB).

#define NPTS  8192
#define CHN   64
#define NB    2
#define KF    18
#define KC    20
#define KOUT  9
#define TILES 128
#define PADQ  68
#define PADD  65

template <int KK>
__device__ __forceinline__ void ins_val(float v, int ix, float (&d)[KK], int (&id)[KK]) {
  if (v < d[KK - 1]) {
#pragma unroll
    for (int k = KK - 1; k >= 1; --k) {
      const bool up = d[k - 1] > v;
      const bool here = (!up) && (d[k] > v);
      d[k] = up ? d[k - 1] : (here ? v : d[k]);
      id[k] = up ? id[k - 1] : (here ? ix : id[k]);
    }
    if (d[0] > v) { d[0] = v; id[0] = ix; }
  }
}

template <int KK>
__device__ __forceinline__ void ins_lex(float v, int ix, float (&d)[KK], int (&id)[KK]) {
  if ((v < d[KK - 1]) || (v == d[KK - 1] && ix < id[KK - 1])) {
#pragma unroll
    for (int k = KK - 1; k >= 1; --k) {
      const bool up = (d[k - 1] > v) || (d[k - 1] == v && id[k - 1] > ix);
      const bool lt = (d[k] > v) || (d[k] == v && id[k] > ix);
      const bool here = (!up) && lt;
      d[k] = up ? d[k - 1] : (here ? v : d[k]);
      id[k] = up ? id[k - 1] : (here ? ix : id[k]);
    }
    if ((d[0] > v) || (d[0] == v && id[0] > ix)) { d[0] = v; id[0] = ix; }
  }
}

// ---------------- kernel 1: np-faithful normalize + pairwise sq ----------------
__global__ __launch_bounds__(256) void prep_kernel(
    const float* __restrict__ x, float* __restrict__ pts, float* __restrict__ sq) {
  const int b = blockIdx.x >> 5;
  const int n = ((blockIdx.x & 31) << 8) + threadIdx.x;
  const float* __restrict__ xb = x + (size_t)b * CHN * NPTS + n;
  float v[CHN];
  // norm: np.sum(x*x, axis=1) on strided axis = sequential ascending c,
  // rounded squares, rounded adds, init 0. NO fma.
  float ss = 0.f;
#pragma unroll
  for (int c = 0; c < CHN; ++c) {
    v[c] = xb[(size_t)c * NPTS];
    ss = __fadd_rn(ss, __fmul_rn(v[c], v[c]));
  }
  const float den = fmaxf(__fsqrt_rn(ss), 1e-12f);   // np.maximum(np.sqrt, 1e-12)
#pragma unroll
  for (int c = 0; c < CHN; ++c) v[c] = __fdiv_rn(v[c], den);
  // sq: np.sum(tmp, axis=-1) contiguous = numpy pairwise, n=64:
  // r[j] = sum_i tmp[j+8i] sequential; combine ((r0+r1)+(r2+r3))+((r4+r5)+(r6+r7))
  float r[8];
#pragma unroll
  for (int j = 0; j < 8; ++j) r[j] = __fmul_rn(v[j], v[j]);
#pragma unroll
  for (int blk = 1; blk < 8; ++blk)
#pragma unroll
    for (int j = 0; j < 8; ++j)
      r[j] = __fadd_rn(r[j], __fmul_rn(v[8 * blk + j], v[8 * blk + j]));
  const float t0 = __fadd_rn(r[0], r[1]);
  const float t1 = __fadd_rn(r[2], r[3]);
  const float t2 = __fadd_rn(r[4], r[5]);
  const float t3 = __fadd_rn(r[6], r[7]);
  sq[(b << 13) + n] = __fadd_rn(__fadd_rn(t0, t1), __fadd_rn(t2, t3));
  float4* dst = (float4*)(pts + (size_t)(b * NPTS + n) * CHN);
#pragma unroll
  for (int u = 0; u < 16; ++u)
    dst[u] = make_float4(v[4 * u], v[4 * u + 1], v[4 * u + 2], v[4 * u + 3]);
}

// ---------------- kernel 2: GEMM candidates + exact-np rescore ----------------
__global__ __launch_bounds__(256) void knn_kernel(
    const float* __restrict__ pts, const float* __restrict__ sq,
    int* __restrict__ out) {
  // manual carve: qs[64*68] | ps[64*68] | dt[64*65] | sqp[64]
  __shared__ __align__(16) float smem[64 * PADQ * 2 + 64 * PADD + 64];
  float* qs = smem;
  float* ps = smem + 64 * PADQ;
  float* dt = smem + 64 * PADQ * 2;
  float* sqp = smem + 64 * PADQ * 2 + 64 * PADD;
  // post-loop overlays (qs/ps/dt dead by then)
  float* vex = smem;                 // [256][18] f32
  int* iex = (int*)(smem + 256 * KF);  // [256][18] int

  const int tid = threadIdx.x;
  const int v = ((blockIdx.x & 7) << 5) + (blockIdx.x >> 3);  // XCD chunking
  const int b = v >> 7;
  const int qbase = (v & 127) << 6;
  const float* __restrict__ pb = pts + ((size_t)b << 19);
  const float* __restrict__ sqb = sq + (b << 13);

  const int sr = tid >> 2, ssub = tid & 3;   // staging/select/rescore mapping
  const int tx = tid & 15, ty = tid >> 4;    // GEMM mapping

  // ---- prologue: qs, ps(tile 0), sqp
  {
    const float4* qsrc = (const float4*)(pb + (size_t)(qbase + sr) * CHN + ssub * 16);
    float4* qdst = (float4*)(qs + sr * PADQ + ssub * 16);
#pragma unroll
    for (int k = 0; k < 4; ++k) qdst[k] = qsrc[k];
    const float4* p0 = (const float4*)(pb + (size_t)sr * CHN + ssub * 16);
    float4* pdst = (float4*)(ps + sr * PADQ + ssub * 16);
#pragma unroll
    for (int k = 0; k < 4; ++k) pdst[k] = p0[k];
    if (tid < 64) sqp[tid] = sqb[tid];
  }
  __syncthreads();

  float d[KC];
  int id[KC];
#pragma unroll
  for (int k = 0; k < KC; ++k) { d[k] = 3.0e38f; id[k] = 0; }

  for (int t = 0; t < TILES; ++t) {
    // stage next tile into regs (written after barrier)
    float4 st[4];
    float sqv = 0.f;
    const bool more = (t + 1) < TILES;
    if (more) {
      const float4* nsrc =
          (const float4*)(pb + ((size_t)(t + 1) * 64 + sr) * CHN + ssub * 16);
#pragma unroll
      for (int k = 0; k < 4; ++k) st[k] = nsrc[k];
      if (tid < 64) sqv = sqb[((t + 1) << 6) + tid];
    }
    // fast fp32 GEMM (approx keys; fma ok)
    float acc[4][4];
#pragma unroll
    for (int i = 0; i < 4; ++i)
#pragma unroll
      for (int j = 0; j < 4; ++j) acc[i][j] = 0.f;
    const float* qb0 = qs + (ty << 2) * PADQ;
#pragma unroll
    for (int c4 = 0; c4 < 16; ++c4) {
      float4 qv[4], pv[4];
#pragma unroll
      for (int i = 0; i < 4; ++i)
        qv[i] = *(const float4*)(qb0 + i * PADQ + (c4 << 2));
#pragma unroll
      for (int j = 0; j < 4; ++j)
        pv[j] = *(const float4*)(ps + (tx + (j << 4)) * PADQ + (c4 << 2));
#pragma unroll
      for (int i = 0; i < 4; ++i)
#pragma unroll
        for (int j = 0; j < 4; ++j)
          acc[i][j] = fmaf(qv[i].x, pv[j].x,
                      fmaf(qv[i].y, pv[j].y,
                      fmaf(qv[i].z, pv[j].z,
                      fmaf(qv[i].w, pv[j].w, acc[i][j]))));
    }
    // approx keys: sq_m - 2*dot (row-constant sq_n dropped; order-preserving)
#pragma unroll
    for (int j = 0; j < 4; ++j) {
      const int m = tx + (j << 4);
      const float sqm = sqp[m];
#pragma unroll
      for (int i = 0; i < 4; ++i)
        dt[((ty << 2) + i) * PADD + m] = fmaf(-2.f, acc[i][j], sqm);
    }
    __syncthreads();
    // select: thread (sr,ssub) scans m = ssub+4u ascending -> stable top-20
    {
      const float* dr = dt + sr * PADD;
      const int mb = t << 6;
#pragma unroll 2
      for (int u = 0; u < 16; ++u) {
        const int m = ssub + (u << 2);
        ins_val<KC>(dr[m], mb + m, d, id);
      }
    }
    if (more) {
      float4* pdst = (float4*)(ps + sr * PADQ + ssub * 16);
#pragma unroll
      for (int k = 0; k < 4; ++k) pdst[k] = st[k];
      if (tid < 64) sqp[tid] = sqv;
    }
    __syncthreads();
  }

  // ---- rescore own 20 candidates with bit-exact np-fp32 distance
  float d2[KF];
  int i2[KF];
#pragma unroll
  for (int k = 0; k < KF; ++k) { d2[k] = 3.0e38f; i2[k] = 0x7fffffff; }
  const float sqn_v = sqb[qbase + sr];
  const float* qrow = qs + sr * PADQ;
  for (int k = 0; k < KC; ++k) {
    const int ix = id[k];
    const float* pvec = pb + (size_t)ix * CHN;
    // einsum replica: c ascending, rounded mul + rounded add, init 0, no fma
    float dot = 0.f;
#pragma unroll
    for (int c = 0; c < CHN; ++c)
      dot = __fadd_rn(dot, __fmul_rn(qrow[c], pvec[c]));
    // dist = (sq_n - (2*dot)) + sq_m, elementwise fp32
    const float dist =
        __fadd_rn(__fsub_rn(sqn_v, __fmul_rn(2.0f, dot)), sqb[ix]);
    ins_lex<KF>(dist, ix, d2, i2);
  }
  __syncthreads();   // qs/ps/dt now dead -> overlay
#pragma unroll
  for (int k = 0; k < KF; ++k) {
    vex[tid * KF + k] = d2[k];
    iex[tid * KF + k] = i2[k];
  }
  __syncthreads();

  // ---- final merge: 4 lanes' exact lists per row, lex (val, idx)
  if (tid < 64) {
    float md[KF];
    int mi[KF];
#pragma unroll
    for (int k = 0; k < KF; ++k) { md[k] = 3.0e38f; mi[k] = 0x7fffffff; }
    for (int sub = 0; sub < 4; ++sub)
      for (int k = 0; k < KF; ++k) {
        const int base = ((tid << 2) + sub) * KF + k;
        ins_lex<KF>(vex[base], iex[base], md, mi);
      }
    const int n = qbase + tid;
    int* o0 = out + (b * NPTS + n) * KOUT;   // plane 0: nn_idx[::2]
    int* o1 = o0 + NB * NPTS * KOUT;         // plane 1: center idx
#pragma unroll
    for (int k = 0; k < KOUT; ++k) {
      o0[k] = mi[2 * k];
      o1[k] = n;
    }
  }
}

// ---------------- launcher ----------------
extern "C" void kernel_launch(void* const* d_in, const int* in_sizes, int n_in,
                              void* d_out, int out_size, void* d_ws, size_t ws_size,
                              hipStream_t stream) {
  const float* x = (const float*)d_in[0];
  float* pts = (float*)d_ws;                          // 4 MB
  float* sqg = pts + (size_t)NB * NPTS * CHN;         // 64 KB
  int* out = (int*)d_out;
  prep_kernel<<<dim3(64), dim3(256), 0, stream>>>(x, pts, sqg);
  knn_kernel<<<dim3(256), dim3(256), 0, stream>>>(pts, sqg, out);
}

// Round 4
// 936.428 us; speedup vs baseline: 2.0454x; 2.0454x over previous
//
#include <hip/hip_runtime.h>

// Dense dilated KNN graph. B=2, C=64, N=8192, k_total=18, keep ::2 -> 9.
// r4: 3-way point-split (768 blocks, 3/CU), u64-packed select, candidate
// indices to ws, bit-exact np-fp32 rescore in finalize kernel.
// ws: ptsn [B][N][64] f32 (4MB) | sqnp [B][N] f32 (64KB) | cand [B*N][60] i32 (3.9MB)

#define NPTS  8192
#define CHN   64
#define NB    2
#define KF    18
#define KC    20
#define KOUT  9
#define PADQ  68
#define PADD  65

typedef unsigned long long u64;

__device__ __forceinline__ unsigned mono32(float f) {
  const unsigned u = __float_as_uint(f);
  return (u & 0x80000000u) ? ~u : (u | 0x80000000u);
}

// stable (val, idx) top-K via packed u64 keys; strict < keeps lower idx on ties
template <int KK>
__device__ __forceinline__ void ins64(u64 key, u64 (&d)[KK]) {
  if (key < d[KK - 1]) {
#pragma unroll
    for (int k = KK - 1; k >= 1; --k) {
      const bool up = d[k - 1] > key;
      const bool here = (!up) && (d[k] > key);
      d[k] = up ? d[k - 1] : (here ? key : d[k]);
    }
    if (d[0] > key) d[0] = key;
  }
}

// ---------------- kernel 1: np-faithful normalize + pairwise sq ----------------
__global__ __launch_bounds__(256) void prep_kernel(
    const float* __restrict__ x, float* __restrict__ pts, float* __restrict__ sq) {
  const int b = blockIdx.x >> 5;
  const int n = ((blockIdx.x & 31) << 8) + threadIdx.x;
  const float* __restrict__ xb = x + (size_t)b * CHN * NPTS + n;
  float v[CHN];
  float ss = 0.f;
#pragma unroll
  for (int c = 0; c < CHN; ++c) {
    v[c] = xb[(size_t)c * NPTS];
    ss = __fadd_rn(ss, __fmul_rn(v[c], v[c]));
  }
  const float den = fmaxf(__fsqrt_rn(ss), 1e-12f);
#pragma unroll
  for (int c = 0; c < CHN; ++c) v[c] = __fdiv_rn(v[c], den);
  // numpy pairwise sum, n=64: 8 accumulators stride 8, fixed combine tree
  float r[8];
#pragma unroll
  for (int j = 0; j < 8; ++j) r[j] = __fmul_rn(v[j], v[j]);
#pragma unroll
  for (int blk = 1; blk < 8; ++blk)
#pragma unroll
    for (int j = 0; j < 8; ++j)
      r[j] = __fadd_rn(r[j], __fmul_rn(v[8 * blk + j], v[8 * blk + j]));
  const float t0 = __fadd_rn(r[0], r[1]);
  const float t1 = __fadd_rn(r[2], r[3]);
  const float t2 = __fadd_rn(r[4], r[5]);
  const float t3 = __fadd_rn(r[6], r[7]);
  sq[(b << 13) + n] = __fadd_rn(__fadd_rn(t0, t1), __fadd_rn(t2, t3));
  float4* dst = (float4*)(pts + (size_t)(b * NPTS + n) * CHN);
#pragma unroll
  for (int u = 0; u < 16; ++u)
    dst[u] = make_float4(v[4 * u], v[4 * u + 1], v[4 * u + 2], v[4 * u + 3]);
}

// ---------------- kernel 2: per-part GEMM + top-20 candidates ----------------
__global__ __launch_bounds__(256) void knn_part_kernel(
    const float* __restrict__ pts, const float* __restrict__ sq,
    int* __restrict__ cand) {
  __shared__ __align__(16) float smem[64 * PADQ * 2 + 64 * PADD + 64];
  float* qs = smem;
  float* ps = smem + 64 * PADQ;
  float* dt = smem + 64 * PADQ * 2;
  float* sqp = smem + 64 * PADQ * 2 + 64 * PADD;
  u64* cl = (u64*)smem;  // post-loop overlay: [256][20] u64 = 40 KB

  const int tid = threadIdx.x;
  // XCD-chunk swizzle (768 = 8 * 96, bijective); vb = part*256 + w
  const int vb = ((blockIdx.x & 7) * 96) + (blockIdx.x >> 3);
  const int part = vb >> 8;
  const int w = vb & 255;
  const int b = w >> 7;
  const int qbase = (w & 127) << 6;
  const int t_lo = part * 43;                  // 0 / 43 / 86
  const int t_hi = (part == 2) ? 128 : (t_lo + 43);
  const float* __restrict__ pb = pts + ((size_t)b << 19);
  const float* __restrict__ sqb = sq + (b << 13);

  const int sr = tid >> 2, ssub = tid & 3;   // staging/select mapping
  const int tx = tid & 15, ty = tid >> 4;    // GEMM mapping

  // ---- prologue: qs, ps(tile t_lo), sqp
  {
    const float4* qsrc = (const float4*)(pb + (size_t)(qbase + sr) * CHN + ssub * 16);
    float4* qdst = (float4*)(qs + sr * PADQ + ssub * 16);
#pragma unroll
    for (int k = 0; k < 4; ++k) qdst[k] = qsrc[k];
    const float4* p0 =
        (const float4*)(pb + ((size_t)(t_lo * 64 + sr)) * CHN + ssub * 16);
    float4* pdst = (float4*)(ps + sr * PADQ + ssub * 16);
#pragma unroll
    for (int k = 0; k < 4; ++k) pdst[k] = p0[k];
    if (tid < 64) sqp[tid] = sqb[(t_lo << 6) + tid];
  }
  __syncthreads();

  u64 d[KC];
#pragma unroll
  for (int k = 0; k < KC; ++k) d[k] = ~0ull;

  for (int t = t_lo; t < t_hi; ++t) {
    // stage next tile into regs (written after barrier)
    float4 st[4];
    float sqv = 0.f;
    const bool more = (t + 1) < t_hi;
    if (more) {
      const float4* nsrc =
          (const float4*)(pb + ((size_t)((t + 1) * 64 + sr)) * CHN + ssub * 16);
#pragma unroll
      for (int k = 0; k < 4; ++k) st[k] = nsrc[k];
      if (tid < 64) sqv = sqb[((t + 1) << 6) + tid];
    }
    // fast fp32 GEMM (approx keys; fma ok)
    float acc[4][4];
#pragma unroll
    for (int i = 0; i < 4; ++i)
#pragma unroll
      for (int j = 0; j < 4; ++j) acc[i][j] = 0.f;
    const float* qb0 = qs + (ty << 2) * PADQ;
#pragma unroll
    for (int c4 = 0; c4 < 16; ++c4) {
      float4 qv[4], pv[4];
#pragma unroll
      for (int i = 0; i < 4; ++i)
        qv[i] = *(const float4*)(qb0 + i * PADQ + (c4 << 2));
#pragma unroll
      for (int j = 0; j < 4; ++j)
        pv[j] = *(const float4*)(ps + (tx + (j << 4)) * PADQ + (c4 << 2));
#pragma unroll
      for (int i = 0; i < 4; ++i)
#pragma unroll
        for (int j = 0; j < 4; ++j)
          acc[i][j] = fmaf(qv[i].x, pv[j].x,
                      fmaf(qv[i].y, pv[j].y,
                      fmaf(qv[i].z, pv[j].z,
                      fmaf(qv[i].w, pv[j].w, acc[i][j]))));
    }
    // approx keys: sq_m - 2*dot (row-constant sq_n dropped; order-preserving)
#pragma unroll
    for (int j = 0; j < 4; ++j) {
      const int m = tx + (j << 4);
      const float sqm = sqp[m];
#pragma unroll
      for (int i = 0; i < 4; ++i)
        dt[((ty << 2) + i) * PADD + m] = fmaf(-2.f, acc[i][j], sqm);
    }
    __syncthreads();
    // select: thread (sr,ssub) scans m = ssub+4u ascending; packed u64 keys
    {
      const float* dr = dt + sr * PADD;
      const int mb = t << 6;
#pragma unroll 2
      for (int u = 0; u < 16; ++u) {
        const int m = ssub + (u << 2);
        const u64 key = ((u64)mono32(dr[m]) << 32) | (unsigned)(mb + m);
        ins64<KC>(key, d);
      }
    }
    if (more) {
      float4* pdst = (float4*)(ps + sr * PADQ + ssub * 16);
#pragma unroll
      for (int k = 0; k < 4; ++k) pdst[k] = st[k];
      if (tid < 64) sqp[tid] = sqv;
    }
    __syncthreads();
  }

  // ---- block merge: 4 lanes x 20 -> top-20 per row-part; emit indices
#pragma unroll
  for (int k = 0; k < KC; ++k) cl[tid * KC + k] = d[k];
  __syncthreads();
  if (tid < 64) {
    u64 md[KC];
#pragma unroll
    for (int k = 0; k < KC; ++k) md[k] = ~0ull;
    for (int sub = 0; sub < 4; ++sub)
      for (int k = 0; k < KC; ++k) ins64<KC>(cl[((tid << 2) + sub) * KC + k], md);
    const int r = (b << 13) + qbase + tid;
    int* cw = cand + (size_t)r * 60 + part * KC;
#pragma unroll
    for (int k = 0; k < KC; ++k) cw[k] = (int)(md[k] & 0xffffffffu);
  }
}

// ---------------- kernel 3: bit-exact np-fp32 rescore + output ----------------
__global__ __launch_bounds__(64) void finalize_kernel(
    const float* __restrict__ pts, const float* __restrict__ sq,
    const int* __restrict__ cand, int* __restrict__ out) {
  const int r = blockIdx.x * 64 + threadIdx.x;   // 0..16383
  const int b = r >> 13;
  const int n = r & 8191;
  const float* __restrict__ qrow = pts + ((size_t)r << 6);
  const float sqn = sq[r];
  const int* __restrict__ cr = cand + (size_t)r * 60;
  u64 m18[KF];
#pragma unroll
  for (int k = 0; k < KF; ++k) m18[k] = ~0ull;
  for (int j = 0; j < 60; ++j) {
    const int ix = cr[j];
    const float* __restrict__ pv = pts + ((size_t)((b << 13) + ix) << 6);
    // einsum replica: c ascending, rounded mul + rounded add, init 0, no fma
    float dot = 0.f;
#pragma unroll
    for (int c = 0; c < CHN; ++c)
      dot = __fadd_rn(dot, __fmul_rn(qrow[c], pv[c]));
    const float dist =
        __fadd_rn(__fsub_rn(sqn, __fmul_rn(2.0f, dot)), sq[(b << 13) + ix]);
    const u64 key = ((u64)mono32(dist) << 32) | (unsigned)ix;
    ins64<KF>(key, m18);
  }
  int* o0 = out + (size_t)r * KOUT;            // plane 0: nn_idx[::2]
  int* o1 = o0 + NB * NPTS * KOUT;             // plane 1: center idx
#pragma unroll
  for (int k = 0; k < KOUT; ++k) {
    o0[k] = (int)(m18[2 * k] & 0xffffffffu);
    o1[k] = n;
  }
}

// ---------------- launcher ----------------
extern "C" void kernel_launch(void* const* d_in, const int* in_sizes, int n_in,
                              void* d_out, int out_size, void* d_ws, size_t ws_size,
                              hipStream_t stream) {
  const float* x = (const float*)d_in[0];
  float* pts = (float*)d_ws;                           // 4 MB
  float* sqg = pts + (size_t)NB * NPTS * CHN;          // 64 KB
  int* cand = (int*)(sqg + NB * NPTS);                 // 3.93 MB
  int* out = (int*)d_out;
  prep_kernel<<<dim3(64), dim3(256), 0, stream>>>(x, pts, sqg);
  knn_part_kernel<<<dim3(768), dim3(256), 0, stream>>>(pts, sqg, cand);
  finalize_kernel<<<dim3(256), dim3(64), 0, stream>>>(pts, sqg, cand, out);
}

// Round 5
// 512.807 us; speedup vs baseline: 3.7351x; 1.8261x over previous
//
#include <hip/hip_runtime.h>

// Dense dilated KNN graph. B=2, C=64, N=8192, k_total=18, keep ::2 -> 9.
// r5: select cost attack — u32 quantized keys (20-bit dist | 12-bit local idx),
// per-lane top-12 network, dt pad 68. Exact-np rescore in finalize unchanged.
// ws: ptsn [B][N][64] f32 (4MB) | sqnp [B][N] f32 (64KB) | cand [B*N][60] i32 (3.9MB)

#define NPTS  8192
#define CHN   64
#define NB    2
#define KF    18
#define KC    12     // per-lane candidate list
#define KM    20     // per-part merged candidates
#define KOUT  9
#define PADQ  68
#define PADD  68

typedef unsigned long long u64;

__device__ __forceinline__ unsigned mono32(float f) {
  const unsigned u = __float_as_uint(f);
  return (u & 0x80000000u) ? ~u : (u | 0x80000000u);
}

// top-K of u32 keys, ascending; unique keys (idx embedded) => ties impossible
template <int KK>
__device__ __forceinline__ void ins32(unsigned key, unsigned (&d)[KK]) {
  if (key < d[KK - 1]) {
#pragma unroll
    for (int k = KK - 1; k >= 1; --k) {
      const bool up = d[k - 1] > key;
      const bool here = (!up) && (d[k] > key);
      d[k] = up ? d[k - 1] : (here ? key : d[k]);
    }
    if (d[0] > key) d[0] = key;
  }
}

// stable (val, idx) top-K via packed u64 keys (finalize only)
template <int KK>
__device__ __forceinline__ void ins64(u64 key, u64 (&d)[KK]) {
  if (key < d[KK - 1]) {
#pragma unroll
    for (int k = KK - 1; k >= 1; --k) {
      const bool up = d[k - 1] > key;
      const bool here = (!up) && (d[k] > key);
      d[k] = up ? d[k - 1] : (here ? key : d[k]);
    }
    if (d[0] > key) d[0] = key;
  }
}

// ---------------- kernel 1: np-faithful normalize + pairwise sq ----------------
__global__ __launch_bounds__(256) void prep_kernel(
    const float* __restrict__ x, float* __restrict__ pts, float* __restrict__ sq) {
  const int b = blockIdx.x >> 5;
  const int n = ((blockIdx.x & 31) << 8) + threadIdx.x;
  const float* __restrict__ xb = x + (size_t)b * CHN * NPTS + n;
  float v[CHN];
  float ss = 0.f;
#pragma unroll
  for (int c = 0; c < CHN; ++c) {
    v[c] = xb[(size_t)c * NPTS];
    ss = __fadd_rn(ss, __fmul_rn(v[c], v[c]));
  }
  const float den = fmaxf(__fsqrt_rn(ss), 1e-12f);
#pragma unroll
  for (int c = 0; c < CHN; ++c) v[c] = __fdiv_rn(v[c], den);
  // numpy pairwise sum, n=64: 8 accumulators stride 8, fixed combine tree
  float r[8];
#pragma unroll
  for (int j = 0; j < 8; ++j) r[j] = __fmul_rn(v[j], v[j]);
#pragma unroll
  for (int blk = 1; blk < 8; ++blk)
#pragma unroll
    for (int j = 0; j < 8; ++j)
      r[j] = __fadd_rn(r[j], __fmul_rn(v[8 * blk + j], v[8 * blk + j]));
  const float t0 = __fadd_rn(r[0], r[1]);
  const float t1 = __fadd_rn(r[2], r[3]);
  const float t2 = __fadd_rn(r[4], r[5]);
  const float t3 = __fadd_rn(r[6], r[7]);
  sq[(b << 13) + n] = __fadd_rn(__fadd_rn(t0, t1), __fadd_rn(t2, t3));
  float4* dst = (float4*)(pts + (size_t)(b * NPTS + n) * CHN);
#pragma unroll
  for (int u = 0; u < 16; ++u)
    dst[u] = make_float4(v[4 * u], v[4 * u + 1], v[4 * u + 2], v[4 * u + 3]);
}

// ---------------- kernel 2: per-part GEMM + top-candidates ----------------
__global__ __launch_bounds__(256) void knn_part_kernel(
    const float* __restrict__ pts, const float* __restrict__ sq,
    int* __restrict__ cand) {
  __shared__ __align__(16) float smem[64 * PADQ * 2 + 64 * PADD + 64];
  float* qs = smem;
  float* ps = smem + 64 * PADQ;
  unsigned* dtu = (unsigned*)(smem + 64 * PADQ * 2);     // packed u32 keys
  float* sqp = smem + 64 * PADQ * 2 + 64 * PADD;
  unsigned* cl = (unsigned*)smem;  // post-loop overlay: [256][12] u32 = 12 KB

  const int tid = threadIdx.x;
  // XCD-chunk swizzle (768 = 8 * 96, bijective); vb = part*256 + w
  const int vb = ((blockIdx.x & 7) * 96) + (blockIdx.x >> 3);
  const int part = vb >> 8;
  const int w = vb & 255;
  const int b = w >> 7;
  const int qbase = (w & 127) << 6;
  const int t_lo = part * 43;                  // 0 / 43 / 86
  const int t_hi = (part == 2) ? 128 : (t_lo + 43);
  const float* __restrict__ pb = pts + ((size_t)b << 19);
  const float* __restrict__ sqb = sq + (b << 13);

  const int sr = tid >> 2, ssub = tid & 3;   // staging/select mapping
  const int tx = tid & 15, ty = tid >> 4;    // GEMM mapping

  // ---- prologue: qs, ps(tile t_lo), sqp
  {
    const float4* qsrc = (const float4*)(pb + (size_t)(qbase + sr) * CHN + ssub * 16);
    float4* qdst = (float4*)(qs + sr * PADQ + ssub * 16);
#pragma unroll
    for (int k = 0; k < 4; ++k) qdst[k] = qsrc[k];
    const float4* p0 =
        (const float4*)(pb + ((size_t)(t_lo * 64 + sr)) * CHN + ssub * 16);
    float4* pdst = (float4*)(ps + sr * PADQ + ssub * 16);
#pragma unroll
    for (int k = 0; k < 4; ++k) pdst[k] = p0[k];
    if (tid < 64) sqp[tid] = sqb[(t_lo << 6) + tid];
  }
  __syncthreads();

  unsigned d[KC];
#pragma unroll
  for (int k = 0; k < KC; ++k) d[k] = 0xffffffffu;

  for (int t = t_lo; t < t_hi; ++t) {
    // stage next tile into regs (written after barrier)
    float4 st[4];
    float sqv = 0.f;
    const bool more = (t + 1) < t_hi;
    if (more) {
      const float4* nsrc =
          (const float4*)(pb + ((size_t)((t + 1) * 64 + sr)) * CHN + ssub * 16);
#pragma unroll
      for (int k = 0; k < 4; ++k) st[k] = nsrc[k];
      if (tid < 64) sqv = sqb[((t + 1) << 6) + tid];
    }
    // fast fp32 GEMM (approx keys; fma ok)
    float acc[4][4];
#pragma unroll
    for (int i = 0; i < 4; ++i)
#pragma unroll
      for (int j = 0; j < 4; ++j) acc[i][j] = 0.f;
    const float* qb0 = qs + (ty << 2) * PADQ;
#pragma unroll
    for (int c4 = 0; c4 < 16; ++c4) {
      float4 qv[4], pv[4];
#pragma unroll
      for (int i = 0; i < 4; ++i)
        qv[i] = *(const float4*)(qb0 + i * PADQ + (c4 << 2));
#pragma unroll
      for (int j = 0; j < 4; ++j)
        pv[j] = *(const float4*)(ps + (tx + (j << 4)) * PADQ + (c4 << 2));
#pragma unroll
      for (int i = 0; i < 4; ++i)
#pragma unroll
        for (int j = 0; j < 4; ++j)
          acc[i][j] = fmaf(qv[i].x, pv[j].x,
                      fmaf(qv[i].y, pv[j].y,
                      fmaf(qv[i].z, pv[j].z,
                      fmaf(qv[i].w, pv[j].w, acc[i][j]))));
    }
    // packed keys: top-20 bits of mono32(sq_m - 2*dot) | 12-bit local idx
    const int lbase = (t - t_lo) << 6;
#pragma unroll
    for (int j = 0; j < 4; ++j) {
      const int m = tx + (j << 4);
      const float sqm = sqp[m];
#pragma unroll
      for (int i = 0; i < 4; ++i) {
        const float dist = fmaf(-2.f, acc[i][j], sqm);
        dtu[((ty << 2) + i) * PADD + m] =
            (mono32(dist) & 0xfffff000u) | (unsigned)(lbase + m);
      }
    }
    __syncthreads();
    // select: thread (sr,ssub) scans m = ssub+4u; u32 network
    {
      const unsigned* dr = dtu + sr * PADD;
#pragma unroll 2
      for (int u = 0; u < 16; ++u) {
        ins32<KC>(dr[ssub + (u << 2)], d);
      }
    }
    if (more) {
      float4* pdst = (float4*)(ps + sr * PADQ + ssub * 16);
#pragma unroll
      for (int k = 0; k < 4; ++k) pdst[k] = st[k];
      if (tid < 64) sqp[tid] = sqv;
    }
    __syncthreads();
  }

  // ---- block merge: 4 lanes x 12 -> top-20 per row-part; emit global indices
#pragma unroll
  for (int k = 0; k < KC; ++k) cl[tid * KC + k] = d[k];
  __syncthreads();
  if (tid < 64) {
    unsigned md[KM];
#pragma unroll
    for (int k = 0; k < KM; ++k) md[k] = 0xffffffffu;
    for (int sub = 0; sub < 4; ++sub)
      for (int k = 0; k < KC; ++k) ins32<KM>(cl[((tid << 2) + sub) * KC + k], md);
    const int r = (b << 13) + qbase + tid;
    int* cw = cand + (size_t)r * 60 + part * KM;
#pragma unroll
    for (int k = 0; k < KM; ++k)
      cw[k] = (t_lo << 6) + (int)(md[k] & 0xfffu);     // decode local -> global
  }
}

// ---------------- kernel 3: bit-exact np-fp32 rescore + output ----------------
__global__ __launch_bounds__(64) void finalize_kernel(
    const float* __restrict__ pts, const float* __restrict__ sq,
    const int* __restrict__ cand, int* __restrict__ out) {
  const int r = blockIdx.x * 64 + threadIdx.x;   // 0..16383
  const int b = r >> 13;
  const int n = r & 8191;
  const float* __restrict__ qrow = pts + ((size_t)r << 6);
  const float sqn = sq[r];
  const int* __restrict__ cr = cand + (size_t)r * 60;
  u64 m18[KF];
#pragma unroll
  for (int k = 0; k < KF; ++k) m18[k] = ~0ull;
  for (int j = 0; j < 60; ++j) {
    const int ix = cr[j];
    const float* __restrict__ pv = pts + ((size_t)((b << 13) + ix) << 6);
    // einsum replica: c ascending, rounded mul + rounded add, init 0, no fma
    float dot = 0.f;
#pragma unroll
    for (int c = 0; c < CHN; ++c)
      dot = __fadd_rn(dot, __fmul_rn(qrow[c], pv[c]));
    const float dist =
        __fadd_rn(__fsub_rn(sqn, __fmul_rn(2.0f, dot)), sq[(b << 13) + ix]);
    const u64 key = ((u64)mono32(dist) << 32) | (unsigned)ix;
    ins64<KF>(key, m18);
  }
  int* o0 = out + (size_t)r * KOUT;            // plane 0: nn_idx[::2]
  int* o1 = o0 + NB * NPTS * KOUT;             // plane 1: center idx
#pragma unroll
  for (int k = 0; k < KOUT; ++k) {
    o0[k] = (int)(m18[2 * k] & 0xffffffffu);
    o1[k] = n;
  }
}

// ---------------- launcher ----------------
extern "C" void kernel_launch(void* const* d_in, const int* in_sizes, int n_in,
                              void* d_out, int out_size, void* d_ws, size_t ws_size,
                              hipStream_t stream) {
  const float* x = (const float*)d_in[0];
  float* pts = (float*)d_ws;                           // 4 MB
  float* sqg = pts + (size_t)NB * NPTS * CHN;          // 64 KB
  int* cand = (int*)(sqg + NB * NPTS);                 // 3.93 MB
  int* out = (int*)d_out;
  prep_kernel<<<dim3(64), dim3(256), 0, stream>>>(x, pts, sqg);
  knn_part_kernel<<<dim3(768), dim3(256), 0, stream>>>(pts, sqg, cand);
  finalize_kernel<<<dim3(256), dim3(64), 0, stream>>>(pts, sqg, cand, out);
}

// Round 8
// 273.058 us; speedup vs baseline: 7.0145x; 1.8780x over previous
//
#include <hip/hip_runtime.h>

// Dense dilated KNN graph. B=2, C=64, N=8192, k_total=18, keep ::2 -> 9.
// r8: r7 + THE fix: double-buffer parity must be relative to t_lo
// (cur = (t - t_lo) & 1). Part 1 (t_lo=43, odd) was reading uninitialized
// LDS for all its tiles in r6/r7.
// Split-bf16 MFMA (hh+hl+lh), XOR-swizzled packed LDS tiles, branchless
// min/max top-K, u32 quantized keys. Exact-np rescore in finalize.
// ws: ptsn [B][N][64] f32 (4MB) | sqnp [B][N] f32 (64KB) | cand [B*N][60] i32

#define NPTS  8192
#define CHN   64
#define NB    2
#define KF    18
#define KC    12     // per-lane candidate list
#define KM    20     // per-part merged candidates
#define KOUT  9

typedef unsigned u32;
typedef unsigned long long u64;
typedef __attribute__((ext_vector_type(4))) unsigned u32x4;
typedef __attribute__((ext_vector_type(8))) short bf16x8;
typedef __attribute__((ext_vector_type(4))) float f32x4;

__device__ __forceinline__ u32 umin32(u32 a, u32 b) { return a < b ? a : b; }
__device__ __forceinline__ u32 umax32(u32 a, u32 b) { return a > b ? a : b; }

// fp32 -> packed u32: bits 16-31 = bf16(hi=trunc(v)), bits 0-15 = bf16(trunc(v-hi))
__device__ __forceinline__ u32 pack_split(float v) {
  const u32 hv = __float_as_uint(v) & 0xffff0000u;
  const float lo = v - __uint_as_float(hv);          // exact (Sterbenz)
  return hv | (__float_as_uint(lo) >> 16);
}

__device__ __forceinline__ u32 mono32(float f) {
  const u32 u = __float_as_uint(f);
  const u32 s = (u32)((int)u >> 31);
  return u ^ (s | 0x80000000u);
}

// branchless sorted-ascending top-K insert: 2 VALU per stage
template <int KK>
__device__ __forceinline__ void insmm(u32 key, u32 (&d)[KK]) {
#pragma unroll
  for (int k = KK - 1; k >= 1; --k) d[k] = umax32(d[k - 1], umin32(d[k], key));
  d[0] = umin32(d[0], key);
}

// stable (val, idx) top-K via packed u64 keys (finalize only)
template <int KK>
__device__ __forceinline__ void ins64(u64 key, u64 (&d)[KK]) {
  if (key < d[KK - 1]) {
#pragma unroll
    for (int k = KK - 1; k >= 1; --k) {
      const bool up = d[k - 1] > key;
      const bool here = (!up) && (d[k] > key);
      d[k] = up ? d[k - 1] : (here ? key : d[k]);
    }
    if (d[0] > key) d[0] = key;
  }
}

// unpack 8 packed u32 -> hi frag + lo frag (8 bf16 each), shift-based
__device__ __forceinline__ void unpack_pair(u32x4 r0, u32x4 r1,
                                            bf16x8& fh, bf16x8& fl) {
  u32x4 h, l;
  h.x = (r0.x >> 16) | (r0.y & 0xffff0000u);
  h.y = (r0.z >> 16) | (r0.w & 0xffff0000u);
  h.z = (r1.x >> 16) | (r1.y & 0xffff0000u);
  h.w = (r1.z >> 16) | (r1.w & 0xffff0000u);
  l.x = (r0.x & 0xffffu) | (r0.y << 16);
  l.y = (r0.z & 0xffffu) | (r0.w << 16);
  l.z = (r1.x & 0xffffu) | (r1.y << 16);
  l.w = (r1.z & 0xffffu) | (r1.w << 16);
  fh = __builtin_bit_cast(bf16x8, h);
  fl = __builtin_bit_cast(bf16x8, l);
}

// ---------------- kernel 1: np-faithful normalize + pairwise sq ----------------
__global__ __launch_bounds__(256) void prep_kernel(
    const float* __restrict__ x, float* __restrict__ pts, float* __restrict__ sq) {
  const int b = blockIdx.x >> 5;
  const int n = ((blockIdx.x & 31) << 8) + threadIdx.x;
  const float* __restrict__ xb = x + (size_t)b * CHN * NPTS + n;
  float v[CHN];
  float ss = 0.f;
#pragma unroll
  for (int c = 0; c < CHN; ++c) {
    v[c] = xb[(size_t)c * NPTS];
    ss = __fadd_rn(ss, __fmul_rn(v[c], v[c]));
  }
  const float den = fmaxf(__fsqrt_rn(ss), 1e-12f);
#pragma unroll
  for (int c = 0; c < CHN; ++c) v[c] = __fdiv_rn(v[c], den);
  float r[8];
#pragma unroll
  for (int j = 0; j < 8; ++j) r[j] = __fmul_rn(v[j], v[j]);
#pragma unroll
  for (int blk = 1; blk < 8; ++blk)
#pragma unroll
    for (int j = 0; j < 8; ++j)
      r[j] = __fadd_rn(r[j], __fmul_rn(v[8 * blk + j], v[8 * blk + j]));
  const float t0 = __fadd_rn(r[0], r[1]);
  const float t1 = __fadd_rn(r[2], r[3]);
  const float t2 = __fadd_rn(r[4], r[5]);
  const float t3 = __fadd_rn(r[6], r[7]);
  sq[(b << 13) + n] = __fadd_rn(__fadd_rn(t0, t1), __fadd_rn(t2, t3));
  float4* dst = (float4*)(pts + (size_t)(b * NPTS + n) * CHN);
#pragma unroll
  for (int u = 0; u < 16; ++u)
    dst[u] = make_float4(v[4 * u], v[4 * u + 1], v[4 * u + 2], v[4 * u + 3]);
}

// ---------------- kernel 2: MFMA GEMM + top-candidates ----------------
__global__ __launch_bounds__(256, 3) void knn_part_kernel(
    const float* __restrict__ pts, const float* __restrict__ sq,
    int* __restrict__ cand) {
  __shared__ __align__(16) u32 pp[2][4096];   // packed point tiles (dbuf, swz)
  __shared__ __align__(16) u32 dtu[64 * 68];  // key tile; Q-stage in prologue
  __shared__ float sqp[64];

  const int tid = threadIdx.x;
  const int vb = ((blockIdx.x & 7) * 96) + (blockIdx.x >> 3);
  const int part = vb >> 8;
  const int w = vb & 255;
  const int b = w >> 7;
  const int qbase = (w & 127) << 6;
  const int t_lo = part * 43;                  // 0 / 43 / 86
  const int t_hi = (part == 2) ? 128 : (t_lo + 43);
  const float* __restrict__ pb = pts + ((size_t)b << 19);
  const float* __restrict__ sqb = sq + (b << 13);

  const int sr = tid >> 2, ssub = tid & 3;   // staging/select mapping
  const int lane = tid & 63, wid = tid >> 6; // MFMA mapping
  const int qoff = (wid & 1) << 5;
  const int moff = (wid >> 1) << 5;
  const int l15 = lane & 15;
  const int h4 = lane >> 4;

  // ---- prologue: stage q tile (x -2, packed) -> dtu, p tile t_lo -> pp[0]
  {
    const float4* qsrc =
        (const float4*)(pb + ((size_t)(qbase + sr) << 6) + (ssub << 4));
    const float4* psrc =
        (const float4*)(pb + ((size_t)t_lo << 12) + (sr << 6) + (ssub << 4));
    u32* qw = dtu + (sr << 6);
    u32* pw = pp[0] + (sr << 6);
#pragma unroll
    for (int q = 0; q < 4; ++q) {
      const float4 qv = qsrc[q];
      const float4 pv = psrc[q];
      u32x4 a, c;
      a.x = pack_split(-2.f * qv.x); a.y = pack_split(-2.f * qv.y);
      a.z = pack_split(-2.f * qv.z); a.w = pack_split(-2.f * qv.w);
      c.x = pack_split(pv.x); c.y = pack_split(pv.y);
      c.z = pack_split(pv.z); c.w = pack_split(pv.w);
      const int wofs = ((ssub << 4) + (q << 2)) ^ ((sr & 15) << 2);
      *(u32x4*)(qw + wofs) = a;
      *(u32x4*)(pw + wofs) = c;
    }
    if (tid < 64) sqp[tid] = sqb[(t_lo << 6) + tid];
  }
  __syncthreads();

  // ---- build A fragments (registers, reused all tiles)
  bf16x8 ah[2][2], al[2][2];
#pragma unroll
  for (int g = 0; g < 2; ++g)
#pragma unroll
    for (int s = 0; s < 2; ++s) {
      const int row = qoff + (g << 4) + l15;
      const int w0 = (s << 5) + (h4 << 3);
      const u32* base = dtu + row * 64;
      const u32x4 r0 = *(const u32x4*)(base + (w0 ^ (l15 << 2)));
      const u32x4 r1 = *(const u32x4*)(base + ((w0 + 4) ^ (l15 << 2)));
      unpack_pair(r0, r1, ah[g][s], al[g][s]);
    }
  __syncthreads();   // dtu free for keys now

  u32 d[KC];
#pragma unroll
  for (int k = 0; k < KC; ++k) d[k] = 0xffffffffu;

  for (int t = t_lo; t < t_hi; ++t) {
    const int cur = (t - t_lo) & 1;            // parity RELATIVE to t_lo (r8 fix)
    float4 st[4];
    float sqv = 0.f;
    const bool more = (t + 1) < t_hi;
    if (more) {   // issue next-tile global loads early
      const float4* nsrc = (const float4*)(pb + ((size_t)(t + 1) << 12) +
                                           (sr << 6) + (ssub << 4));
#pragma unroll
      for (int q = 0; q < 4; ++q) st[q] = nsrc[q];
      if (tid < 64) sqv = sqb[((t + 1) << 6) + tid];
    }
    // ---- MFMA: D = (-2Q)*P + sq_m  => D IS the key-dist
    const u32* ppc = pp[cur];
    const int lbase = (t - t_lo) << 6;
#pragma unroll
    for (int f = 0; f < 2; ++f) {
      const int m_l = moff + (f << 4) + l15;
      const float sqm = sqp[m_l];
      f32x4 acc[2];
      acc[0] = (f32x4){sqm, sqm, sqm, sqm};
      acc[1] = acc[0];
#pragma unroll
      for (int s = 0; s < 2; ++s) {
        const int w0 = (s << 5) + (h4 << 3);
        const u32* base = ppc + m_l * 64;
        const u32x4 r0 = *(const u32x4*)(base + (w0 ^ (l15 << 2)));
        const u32x4 r1 = *(const u32x4*)(base + ((w0 + 4) ^ (l15 << 2)));
        bf16x8 bh, bl;
        unpack_pair(r0, r1, bh, bl);
        acc[0] = __builtin_amdgcn_mfma_f32_16x16x32_bf16(ah[0][s], bh, acc[0], 0, 0, 0);
        acc[1] = __builtin_amdgcn_mfma_f32_16x16x32_bf16(ah[1][s], bh, acc[1], 0, 0, 0);
        acc[0] = __builtin_amdgcn_mfma_f32_16x16x32_bf16(al[0][s], bh, acc[0], 0, 0, 0);
        acc[1] = __builtin_amdgcn_mfma_f32_16x16x32_bf16(al[1][s], bh, acc[1], 0, 0, 0);
        acc[0] = __builtin_amdgcn_mfma_f32_16x16x32_bf16(ah[0][s], bl, acc[0], 0, 0, 0);
        acc[1] = __builtin_amdgcn_mfma_f32_16x16x32_bf16(ah[1][s], bl, acc[1], 0, 0, 0);
      }
      const u32 lidx = (u32)(lbase + m_l);
#pragma unroll
      for (int g = 0; g < 2; ++g) {
        const int qg = qoff + (g << 4) + (h4 << 2);
#pragma unroll
        for (int i = 0; i < 4; ++i) {
          const u32 key = (mono32(acc[g][i]) & 0xfffff000u) | lidx;
          dtu[(qg + i) * 68 + m_l] = key;
        }
      }
    }
    __syncthreads();
    // ---- select: lane (sr, ssub) scans 16 contiguous m as 4x b128
    {
      const u32* dr = dtu + sr * 68 + (ssub << 4);
#pragma unroll
      for (int u = 0; u < 4; ++u) {
        const u32x4 k4 = *(const u32x4*)(dr + (u << 2));
        insmm<KC>(k4.x, d);
        insmm<KC>(k4.y, d);
        insmm<KC>(k4.z, d);
        insmm<KC>(k4.w, d);
      }
    }
    if (more) {   // pack + write next point tile
      u32* wp = pp[cur ^ 1] + (sr << 6);
#pragma unroll
      for (int q = 0; q < 4; ++q) {
        u32x4 pk;
        pk.x = pack_split(st[q].x); pk.y = pack_split(st[q].y);
        pk.z = pack_split(st[q].z); pk.w = pack_split(st[q].w);
        *(u32x4*)(wp + (((ssub << 4) + (q << 2)) ^ ((sr & 15) << 2))) = pk;
      }
      if (tid < 64) sqp[tid] = sqv;
    }
    __syncthreads();
  }

  // ---- block merge: 4 lanes x 12 -> top-20 per row-part; emit global indices
  u32* cl = (u32*)pp;
#pragma unroll
  for (int k = 0; k < KC; ++k) cl[tid * KC + k] = d[k];
  __syncthreads();
  if (tid < 64) {
    u32 md[KM];
#pragma unroll
    for (int k = 0; k < KM; ++k) md[k] = 0xffffffffu;
    for (int sub = 0; sub < 4; ++sub)
      for (int k = 0; k < KC; ++k) insmm<KM>(cl[((tid << 2) + sub) * KC + k], md);
    const int r = (b << 13) + qbase + tid;
    int* cw = cand + (size_t)r * 60 + part * KM;
#pragma unroll
    for (int k = 0; k < KM; ++k)
      cw[k] = (t_lo << 6) + (int)(md[k] & 0xfffu);
  }
}

// ---------------- kernel 3: bit-exact np-fp32 rescore + output ----------------
__global__ __launch_bounds__(64) void finalize_kernel(
    const float* __restrict__ pts, const float* __restrict__ sq,
    const int* __restrict__ cand, int* __restrict__ out) {
  const int r = blockIdx.x * 64 + threadIdx.x;   // 0..16383
  const int b = r >> 13;
  const int n = r & 8191;
  const float* __restrict__ qrow = pts + ((size_t)r << 6);
  const float sqn = sq[r];
  const int* __restrict__ cr = cand + (size_t)r * 60;
  u64 m18[KF];
#pragma unroll
  for (int k = 0; k < KF; ++k) m18[k] = ~0ull;
  for (int j = 0; j < 60; ++j) {
    const int ix = cr[j];
    const float* __restrict__ pv = pts + ((size_t)((b << 13) + ix) << 6);
    float dot = 0.f;
#pragma unroll
    for (int c = 0; c < CHN; ++c)
      dot = __fadd_rn(dot, __fmul_rn(qrow[c], pv[c]));
    const float dist =
        __fadd_rn(__fsub_rn(sqn, __fmul_rn(2.0f, dot)), sq[(b << 13) + ix]);
    const u64 key = ((u64)mono32(dist) << 32) | (unsigned)ix;
    ins64<KF>(key, m18);
  }
  int* o0 = out + (size_t)r * KOUT;            // plane 0: nn_idx[::2]
  int* o1 = o0 + NB * NPTS * KOUT;             // plane 1: center idx
#pragma unroll
  for (int k = 0; k < KOUT; ++k) {
    o0[k] = (int)(m18[2 * k] & 0xffffffffu);
    o1[k] = n;
  }
}

// ---------------- launcher ----------------
extern "C" void kernel_launch(void* const* d_in, const int* in_sizes, int n_in,
                              void* d_out, int out_size, void* d_ws, size_t ws_size,
                              hipStream_t stream) {
  const float* x = (const float*)d_in[0];
  float* pts = (float*)d_ws;                           // 4 MB
  float* sqg = pts + (size_t)NB * NPTS * CHN;          // 64 KB
  int* cand = (int*)(sqg + NB * NPTS);                 // 3.93 MB
  int* out = (int*)d_out;
  prep_kernel<<<dim3(64), dim3(256), 0, stream>>>(x, pts, sqg);
  knn_part_kernel<<<dim3(768), dim3(256), 0, stream>>>(pts, sqg, cand);
  finalize_kernel<<<dim3(256), dim3(64), 0, stream>>>(pts, sqg, cand, out);
}

// Round 9
// 245.258 us; speedup vs baseline: 7.8096x; 1.1134x over previous
//
#include <hip/hip_runtime.h>

// Dense dilated KNN graph. B=2, C=64, N=8192, k_total=18, keep ::2 -> 9.
// r9: register-resident select (8 per-row KC=8 lists/lane, static idx),
// ONE barrier per tile (dbuf pp), in-block 3-level merge -> u16 cand,
// widened finalize (4 thr/row). GEMM/staging identical to proven r8.
// ws: ptsn [B][N][64] f32 (4MB) | sqnp f32 (64KB) | cand u16 [B*N][60] (1.97MB)

#define NPTS  8192
#define CHN   64
#define NB    2
#define KF    18
#define KC    8      // per-(row,stream) candidate list depth
#define KM    20     // per-part merged candidates
#define KOUT  9

typedef unsigned u32;
typedef unsigned short u16;
typedef unsigned long long u64;
typedef __attribute__((ext_vector_type(4))) unsigned u32x4;
typedef __attribute__((ext_vector_type(8))) short bf16x8;
typedef __attribute__((ext_vector_type(4))) float f32x4;

__device__ __forceinline__ u32 umin32(u32 a, u32 b) { return a < b ? a : b; }
__device__ __forceinline__ u32 umax32(u32 a, u32 b) { return a > b ? a : b; }

// fp32 -> packed u32: bits16-31 = bf16(trunc(v)), bits0-15 = bf16(trunc(v-hi))
__device__ __forceinline__ u32 pack_split(float v) {
  const u32 hv = __float_as_uint(v) & 0xffff0000u;
  const float lo = v - __uint_as_float(hv);
  return hv | (__float_as_uint(lo) >> 16);
}

__device__ __forceinline__ u32 mono32(float f) {
  const u32 u = __float_as_uint(f);
  const u32 s = (u32)((int)u >> 31);
  return u ^ (s | 0x80000000u);
}

// branchless sorted-ascending top-K insert: 2 VALU per stage
template <int KK>
__device__ __forceinline__ void insmm(u32 key, u32 (&d)[KK]) {
#pragma unroll
  for (int k = KK - 1; k >= 1; --k) d[k] = umax32(d[k - 1], umin32(d[k], key));
  d[0] = umin32(d[0], key);
}

template <int KK>
__device__ __forceinline__ void ins64(u64 key, u64 (&d)[KK]) {
  if (key < d[KK - 1]) {
#pragma unroll
    for (int k = KK - 1; k >= 1; --k) {
      const bool up = d[k - 1] > key;
      const bool here = (!up) && (d[k] > key);
      d[k] = up ? d[k - 1] : (here ? key : d[k]);
    }
    if (d[0] > key) d[0] = key;
  }
}

__device__ __forceinline__ void unpack_pair(u32x4 r0, u32x4 r1,
                                            bf16x8& fh, bf16x8& fl) {
  u32x4 h, l;
  h.x = (r0.x >> 16) | (r0.y & 0xffff0000u);
  h.y = (r0.z >> 16) | (r0.w & 0xffff0000u);
  h.z = (r1.x >> 16) | (r1.y & 0xffff0000u);
  h.w = (r1.z >> 16) | (r1.w & 0xffff0000u);
  l.x = (r0.x & 0xffffu) | (r0.y << 16);
  l.y = (r0.z & 0xffffu) | (r0.w << 16);
  l.z = (r1.x & 0xffffu) | (r1.y << 16);
  l.w = (r1.z & 0xffffu) | (r1.w << 16);
  fh = __builtin_bit_cast(bf16x8, h);
  fl = __builtin_bit_cast(bf16x8, l);
}

// ---------------- kernel 1: np-faithful normalize + pairwise sq ----------------
__global__ __launch_bounds__(128) void prep_kernel(
    const float* __restrict__ x, float* __restrict__ pts, float* __restrict__ sq) {
  const int b = blockIdx.x >> 6;
  const int n = ((blockIdx.x & 63) << 7) + threadIdx.x;
  const float* __restrict__ xb = x + (size_t)b * CHN * NPTS + n;
  float v[CHN];
  float ss = 0.f;
#pragma unroll
  for (int c = 0; c < CHN; ++c) {
    v[c] = xb[(size_t)c * NPTS];
    ss = __fadd_rn(ss, __fmul_rn(v[c], v[c]));
  }
  const float den = fmaxf(__fsqrt_rn(ss), 1e-12f);
#pragma unroll
  for (int c = 0; c < CHN; ++c) v[c] = __fdiv_rn(v[c], den);
  float r[8];
#pragma unroll
  for (int j = 0; j < 8; ++j) r[j] = __fmul_rn(v[j], v[j]);
#pragma unroll
  for (int blk = 1; blk < 8; ++blk)
#pragma unroll
    for (int j = 0; j < 8; ++j)
      r[j] = __fadd_rn(r[j], __fmul_rn(v[8 * blk + j], v[8 * blk + j]));
  const float t0 = __fadd_rn(r[0], r[1]);
  const float t1 = __fadd_rn(r[2], r[3]);
  const float t2 = __fadd_rn(r[4], r[5]);
  const float t3 = __fadd_rn(r[6], r[7]);
  sq[(b << 13) + n] = __fadd_rn(__fadd_rn(t0, t1), __fadd_rn(t2, t3));
  float4* dst = (float4*)(pts + (size_t)(b * NPTS + n) * CHN);
#pragma unroll
  for (int u = 0; u < 16; ++u)
    dst[u] = make_float4(v[4 * u], v[4 * u + 1], v[4 * u + 2], v[4 * u + 3]);
}

// ---------------- kernel 2: MFMA GEMM + reg-select + merge ----------------
__global__ __launch_bounds__(256, 3) void knn_part_kernel(
    const float* __restrict__ pts, const float* __restrict__ sq,
    u16* __restrict__ cand) {
  __shared__ __align__(16) u32 pp[2][4096];   // packed point tiles (dbuf, swz)
  __shared__ __align__(16) u32 dtu[4352];     // Q-stage / M1 scratch
  __shared__ float sqp[2][64];

  const int tid = threadIdx.x;
  const int vb = ((blockIdx.x & 7) * 96) + (blockIdx.x >> 3);
  const int part = vb >> 8;
  const int w = vb & 255;
  const int b = w >> 7;
  const int qbase = (w & 127) << 6;
  const int t_lo = part * 43;                  // 0 / 43 / 86
  const int t_hi = (part == 2) ? 128 : (t_lo + 43);
  const float* __restrict__ pb = pts + ((size_t)b << 19);
  const float* __restrict__ sqb = sq + (b << 13);

  const int sr = tid >> 2, ssub = tid & 3;   // staging mapping
  const int lane = tid & 63, wid = tid >> 6; // MFMA mapping
  const int qoff = (wid & 1) << 5;
  const int moff = (wid >> 1) << 5;
  const int l15 = lane & 15;
  const int h4 = lane >> 4;

  // ---- prologue: stage q tile (packed, UNscaled) -> dtu, p tile t_lo -> pp[0]
  {
    const float4* qsrc =
        (const float4*)(pb + ((size_t)(qbase + sr) << 6) + (ssub << 4));
    const float4* psrc =
        (const float4*)(pb + ((size_t)t_lo << 12) + (sr << 6) + (ssub << 4));
    u32* qw = dtu + (sr << 6);
    u32* pw = pp[0] + (sr << 6);
#pragma unroll
    for (int q = 0; q < 4; ++q) {
      const float4 qv = qsrc[q];
      const float4 pv = psrc[q];
      u32x4 a, c;
      a.x = pack_split(qv.x); a.y = pack_split(qv.y);
      a.z = pack_split(qv.z); a.w = pack_split(qv.w);
      c.x = pack_split(pv.x); c.y = pack_split(pv.y);
      c.z = pack_split(pv.z); c.w = pack_split(pv.w);
      const int wofs = ((ssub << 4) + (q << 2)) ^ ((sr & 15) << 2);
      *(u32x4*)(qw + wofs) = a;
      *(u32x4*)(pw + wofs) = c;
    }
    if (tid < 64) sqp[0][tid] = sqb[(t_lo << 6) + tid];
  }
  __syncthreads();

  // ---- build A fragments (registers, reused all tiles)
  bf16x8 ah[2][2], al[2][2];
#pragma unroll
  for (int g = 0; g < 2; ++g)
#pragma unroll
    for (int s = 0; s < 2; ++s) {
      const int row = qoff + (g << 4) + l15;
      const int w0 = (s << 5) + (h4 << 3);
      const u32* base = dtu + row * 64;
      const u32x4 r0 = *(const u32x4*)(base + (w0 ^ (l15 << 2)));
      const u32x4 r1 = *(const u32x4*)(base + ((w0 + 4) ^ (l15 << 2)));
      unpack_pair(r0, r1, ah[g][s], al[g][s]);
    }
  __syncthreads();

  // per-lane candidate lists: d[g][i][KC]  (static indexing only)
  u32 d[2][4][KC];
#pragma unroll
  for (int g = 0; g < 2; ++g)
#pragma unroll
    for (int i = 0; i < 4; ++i)
#pragma unroll
      for (int k = 0; k < KC; ++k) d[g][i][k] = 0xffffffffu;

  for (int t = t_lo; t < t_hi; ++t) {
    const int cur = (t - t_lo) & 1;
    float4 st[4];
    float sqv = 0.f;
    const bool more = (t + 1) < t_hi;
    if (more) {   // issue next-tile global loads early
      const float4* nsrc = (const float4*)(pb + ((size_t)(t + 1) << 12) +
                                           (sr << 6) + (ssub << 4));
#pragma unroll
      for (int q = 0; q < 4; ++q) st[q] = nsrc[q];
      if (tid < 64) sqv = sqb[((t + 1) << 6) + tid];
    }
    // ---- MFMA + in-register select
    const u32* ppc = pp[cur];
    const int lbase = (t - t_lo) << 6;
#pragma unroll
    for (int f = 0; f < 2; ++f) {
      const int m_l = moff + (f << 4) + l15;
      const float sqm = sqp[cur][m_l];
      f32x4 acc[2];
      acc[0] = (f32x4){0.f, 0.f, 0.f, 0.f};
      acc[1] = acc[0];
#pragma unroll
      for (int s = 0; s < 2; ++s) {
        const int w0 = (s << 5) + (h4 << 3);
        const u32* base = ppc + m_l * 64;
        const u32x4 r0 = *(const u32x4*)(base + (w0 ^ (l15 << 2)));
        const u32x4 r1 = *(const u32x4*)(base + ((w0 + 4) ^ (l15 << 2)));
        bf16x8 bh, bl;
        unpack_pair(r0, r1, bh, bl);
        acc[0] = __builtin_amdgcn_mfma_f32_16x16x32_bf16(ah[0][s], bh, acc[0], 0, 0, 0);
        acc[1] = __builtin_amdgcn_mfma_f32_16x16x32_bf16(ah[1][s], bh, acc[1], 0, 0, 0);
        acc[0] = __builtin_amdgcn_mfma_f32_16x16x32_bf16(al[0][s], bh, acc[0], 0, 0, 0);
        acc[1] = __builtin_amdgcn_mfma_f32_16x16x32_bf16(al[1][s], bh, acc[1], 0, 0, 0);
        acc[0] = __builtin_amdgcn_mfma_f32_16x16x32_bf16(ah[0][s], bl, acc[0], 0, 0, 0);
        acc[1] = __builtin_amdgcn_mfma_f32_16x16x32_bf16(ah[1][s], bl, acc[1], 0, 0, 0);
      }
      const u32 lidx = (u32)(lbase + m_l);
#pragma unroll
      for (int g = 0; g < 2; ++g)
#pragma unroll
        for (int i = 0; i < 4; ++i) {
          const float dist = fmaf(-2.f, acc[g][i], sqm);
          const u32 key = (mono32(dist) & 0xfffff000u) | lidx;
          insmm<KC>(key, d[g][i]);
        }
    }
    // ---- stage write (pp dbuf: no barrier needed before writes)
    if (more) {
      u32* wp = pp[cur ^ 1] + (sr << 6);
#pragma unroll
      for (int q = 0; q < 4; ++q) {
        u32x4 pk;
        pk.x = pack_split(st[q].x); pk.y = pack_split(st[q].y);
        pk.z = pack_split(st[q].z); pk.w = pack_split(st[q].w);
        *(u32x4*)(wp + (((ssub << 4) + (q << 2)) ^ ((sr & 15) << 2))) = pk;
      }
      if (tid < 64) sqp[cur ^ 1][tid] = sqv;
    }
    __syncthreads();   // the ONE barrier per tile
  }

  // ---- 3-level merge, two 32-row chunks (g = chunk)
  u32* mg = (u32*)pp;                        // 8192 u32
  const int rowc_b = ((wid & 1) << 4) + (h4 << 2);
  const int stream = ((wid >> 1) << 4) + l15;
  for (int chunk = 0; chunk < 2; ++chunk) {
    // dump: keys are self-describing; chunk index XOR h4 for bank spread
#pragma unroll
    for (int i = 0; i < 4; ++i) {
      const int cb = (((rowc_b + i) << 5) + stream) << 1;   // even
      u32x4 lo4, hi4;
      lo4.x = d[chunk][i][0]; lo4.y = d[chunk][i][1];
      lo4.z = d[chunk][i][2]; lo4.w = d[chunk][i][3];
      hi4.x = d[chunk][i][4]; hi4.y = d[chunk][i][5];
      hi4.z = d[chunk][i][6]; hi4.w = d[chunk][i][7];
      *(u32x4*)(mg + ((cb ^ h4) << 2)) = lo4;
      *(u32x4*)(mg + (((cb + 1) ^ h4) << 2)) = hi4;
    }
    __syncthreads();
    // M1: 256 thr, (rowc, oct): 4 streams x 8 = 32 keys -> depth-14 -> dtu
    {
      const int rowc = tid >> 3, oct = tid & 7;
      u32 m1[14];
#pragma unroll
      for (int k = 0; k < 14; ++k) m1[k] = 0xffffffffu;
      const u32* rd = mg + ((rowc << 6) + (oct << 3) << 2);
#pragma unroll
      for (int j = 0; j < 8; ++j) {
        const int jj = (j + tid) & 7;
        const u32x4 k4 = *(const u32x4*)(rd + (jj << 2));
        insmm<14>(k4.x, m1);
        insmm<14>(k4.y, m1);
        insmm<14>(k4.z, m1);
        insmm<14>(k4.w, m1);
      }
      u32* wr = dtu + rowc * 112 + oct * 14;
#pragma unroll
      for (int k = 0; k < 14; ++k) wr[k] = m1[k];
    }
    __syncthreads();
    // M2: 64 thr, (rowc, half): 4 octs x 14 = 56 keys -> depth-20 -> mg
    if (tid < 64) {
      const int rowc = tid >> 1, half = tid & 1;
      u32 m2[KM];
#pragma unroll
      for (int k = 0; k < KM; ++k) m2[k] = 0xffffffffu;
      const u32* rd = dtu + rowc * 112 + half * 56;
      for (int j = 0; j < 56; ++j) insmm<KM>(rd[j], m2);
      u32* wr = mg + rowc * 40 + half * KM;
#pragma unroll
      for (int k = 0; k < KM; ++k) wr[k] = m2[k];
    }
    __syncthreads();
    // M3: 32 thr: 40 keys -> top-20 -> cand (u16 global idx)
    if (tid < 32) {
      u32 m3[KM];
#pragma unroll
      for (int k = 0; k < KM; ++k) m3[k] = 0xffffffffu;
      const u32* rd = mg + tid * 40;
      for (int j = 0; j < 40; ++j) insmm<KM>(rd[j], m3);
      const int row = ((tid >> 4) << 5) + (chunk << 4) + (tid & 15);
      const int rg = (b << 13) + qbase + row;
      u16* cw = cand + (size_t)rg * 60 + part * KM;
#pragma unroll
      for (int k = 0; k < KM; ++k)
        cw[k] = (u16)((t_lo << 6) + (m3[k] & 0xfffu));
    }
    __syncthreads();
  }
}

// ---------------- kernel 3: bit-exact np-fp32 rescore + output ----------------
__global__ __launch_bounds__(256) void finalize_kernel(
    const float* __restrict__ pts, const float* __restrict__ sq,
    const u16* __restrict__ cand, int* __restrict__ out) {
  __shared__ u64 ex[64 * 60];
  const int tid = threadIdx.x;
  const int rl = tid >> 2, sub = tid & 3;
  const int row = blockIdx.x * 64 + rl;          // 0..16383
  const int b = row >> 13;
  const int n = row & 8191;
  const float* __restrict__ qrow = pts + ((size_t)row << 6);
  const float sqn = sq[row];
  const u16* __restrict__ cr = cand + (size_t)row * 60 + sub * 15;
  for (int j = 0; j < 15; ++j) {
    const int ix = cr[j];
    const float* __restrict__ pv = pts + ((size_t)((b << 13) + ix) << 6);
    float dot = 0.f;
#pragma unroll
    for (int c = 0; c < CHN; ++c)
      dot = __fadd_rn(dot, __fmul_rn(qrow[c], pv[c]));
    const float dist =
        __fadd_rn(__fsub_rn(sqn, __fmul_rn(2.0f, dot)), sq[(b << 13) + ix]);
    ex[rl * 60 + sub * 15 + j] = ((u64)mono32(dist) << 32) | (unsigned)ix;
  }
  __syncthreads();
  if (tid < 64) {
    u64 m18[KF];
#pragma unroll
    for (int k = 0; k < KF; ++k) m18[k] = ~0ull;
    for (int j = 0; j < 60; ++j) ins64<KF>(ex[tid * 60 + j], m18);
    const int row2 = blockIdx.x * 64 + tid;
    const int n2 = row2 & 8191;
    int* o0 = out + (size_t)row2 * KOUT;
    int* o1 = o0 + NB * NPTS * KOUT;
#pragma unroll
    for (int k = 0; k < KOUT; ++k) {
      o0[k] = (int)(m18[2 * k] & 0xffffffffu);
      o1[k] = n2;
    }
  }
}

// ---------------- launcher ----------------
extern "C" void kernel_launch(void* const* d_in, const int* in_sizes, int n_in,
                              void* d_out, int out_size, void* d_ws, size_t ws_size,
                              hipStream_t stream) {
  const float* x = (const float*)d_in[0];
  float* pts = (float*)d_ws;                           // 4 MB
  float* sqg = pts + (size_t)NB * NPTS * CHN;          // 64 KB
  u16* cand = (u16*)(sqg + NB * NPTS);                 // 1.97 MB
  int* out = (int*)d_out;
  prep_kernel<<<dim3(128), dim3(128), 0, stream>>>(x, pts, sqg);
  knn_part_kernel<<<dim3(768), dim3(256), 0, stream>>>(pts, sqg, cand);
  finalize_kernel<<<dim3(256), dim3(256), 0, stream>>>(pts, sqg, cand, out);
}